// Round 9
// baseline (45.252 us; speedup 1.0000x reference)
//
#include <hip/hip_runtime.h>
#include <stdint.h>

// Problem geometry (reference: 128^3 grid, padded to 130^3, cells = 129^3)
constexpr int DIM    = 128;
constexpr int NCX    = 129;
constexpr int NCELLS = NCX * NCX * NCX;            // 2,146,689 = 8385*256 + 129
constexpr size_t NV_ELEMS = (size_t)NCELLS * 12;   // verts region: 25,760,268 f32
constexpr size_t NT_ELEMS = (size_t)NCELLS * 6;    // tris  region: 12,880,134 f32
// vmask region: NCELLS*4 f32 ; total = 47,227,158 f32 elements

constexpr int BLK = 256;
constexpr int NBV = (NCELLS + BLK - 1) / BLK;          // 8386 verts blocks
constexpr int NBT = NBV;                               // 8386 tris blocks
constexpr int NBM = (NCELLS + 2 * BLK - 1) / (2 * BLK);// 4193 vmask blocks (512 cells)

// per-cell active mask, recomputed from the (L2/L3-resident) grid
__device__ __forceinline__ float cell_mask(const float* __restrict__ grid, int cell) {
    int z  = cell % NCX;
    int tt = cell / NCX;
    int y  = tt % NCX;
    int x  = tt / NCX;
    float cmin = 3.4e38f, cmax = -3.4e38f;
    #pragma unroll
    for (int dx = 0; dx < 2; ++dx) {
        int i = x + dx - 1;
        bool iok = (unsigned)i < (unsigned)DIM;
        #pragma unroll
        for (int dy = 0; dy < 2; ++dy) {
            int j = y + dy - 1;
            bool jok = (unsigned)j < (unsigned)DIM;
            #pragma unroll
            for (int dz = 0; dz < 2; ++dz) {
                int k = z + dz - 1;
                bool kok = (unsigned)k < (unsigned)DIM;
                float v = 1.0f;
                if (iok && jok && kok)
                    v = grid[((size_t)i * DIM + j) * DIM + k];
                cmin = fminf(cmin, v);
                cmax = fmaxf(cmax, v);
            }
        }
    }
    return ((cmin <= 0.0f) && (cmax >= 0.0f)) ? 1.0f : 0.0f;
}

// tris f2 j (cell-local cl=j/3, s=j%3):
//   pair = ((4*cell + A[s])*m, (4*cell + B[s])*m), A={0,2,2}, B={1,0,3}
__device__ __forceinline__ float2 tri_pair(const float* __restrict__ smm,
                                           int c0, int j) {
    int cl = j / 3;
    int s  = j - 3 * cl;
    float mm = smm[cl];
    int base = (c0 + cl) * 4;       // <= 8,586,752 : exact in f32
    int a = (s == 0) ? 0 : 2;
    int b = (s == 0) ? 1 : ((s == 1) ? 0 : 3);
    return make_float2((float)(base + a) * mm, (float)(base + b) * mm);
}

__global__ __launch_bounds__(BLK) void mc_kernel(
    const float* __restrict__ grid,
    const float* __restrict__ deform,
    float*       __restrict__ out)
{
    __shared__ __align__(16) float sbuf[BLK * 12];   // verts stage / mask stage
    const int bid = blockIdx.x;
    const int t   = threadIdx.x;

    if (bid < NBV) {
        // ---------------- verts blocks: one 12 KB contiguous write ----------
        const int c0   = bid * BLK;
        const int cell = c0 + t;
        if (cell < NCELLS) {
            int z  = cell % NCX;
            int tt = cell / NCX;
            int y  = tt % NCX;
            int x  = tt / NCX;
            float m = cell_mask(grid, cell);

            float d0 = 0.f, d1 = 0.f, d2 = 0.f;
            int i = x - 1, j = y - 1, k = z - 1;
            if ((unsigned)i < (unsigned)DIM && (unsigned)j < (unsigned)DIM &&
                (unsigned)k < (unsigned)DIM) {
                const float* b = deform + (((size_t)i * DIM + j) * DIM + k) * 3;
                d0 = b[0]; d1 = b[1]; d2 = b[2];
            }
            float cx = (float)x + 0.5f + d0;
            float cy = (float)y + 0.5f + d1;
            float cz = (float)z + 0.5f + d2;

            // (v - 1)/128 - 1 == v*(1/128) + (-(1/128) - 1)
            constexpr float S = 1.0f / 128.0f;
            constexpr float B = -(1.0f / 128.0f) - 1.0f;
            float ax = fmaf(cx - 0.3f, S, B) * m;   // OFFSET = 0.3
            float bx = fmaf(cx + 0.3f, S, B) * m;
            float ay = fmaf(cy - 0.3f, S, B) * m;
            float by = fmaf(cy + 0.3f, S, B) * m;
            float gz = fmaf(cz,        S, B) * m;

            // stride 48 B tiles the 32 banks exactly -> conflict-free
            float4* v4 = reinterpret_cast<float4*>(sbuf) + t * 3;
            v4[0] = make_float4(ax, ay, gz, bx);
            v4[1] = make_float4(ay, gz, bx, by);
            v4[2] = make_float4(gz, ax, by, gz);
        }
        __syncthreads();

        float4*       gv = reinterpret_cast<float4*>(out + (size_t)c0 * 12);
        const float4* lv = reinterpret_cast<const float4*>(sbuf);
        if (c0 + BLK <= NCELLS) {
            #pragma unroll
            for (int r = 0; r < 3; ++r) gv[t + r * BLK] = lv[t + r * BLK];
        } else {
            const int n = NCELLS - c0;
            for (int i2 = t; i2 < n * 3; i2 += BLK) gv[i2] = lv[i2];
        }

    } else if (bid < NBV + NBT) {
        // ---------------- tris blocks: one 6 KB contiguous write ------------
        const int c0   = (bid - NBV) * BLK;
        const int cell = c0 + t;
        sbuf[t] = (cell < NCELLS) ? cell_mask(grid, cell) : 0.0f;
        __syncthreads();

        if (c0 + BLK <= NCELLS) {
            float4* gt4 = reinterpret_cast<float4*>(out + NV_ELEMS + (size_t)c0 * 6);
            float2 lo = tri_pair(sbuf, c0, 2 * t);
            float2 hi = tri_pair(sbuf, c0, 2 * t + 1);
            gt4[t] = make_float4(lo.x, lo.y, hi.x, hi.y);
            if (t < BLK / 2) {
                int p = BLK + t;
                float2 lo2 = tri_pair(sbuf, c0, 2 * p);
                float2 hi2 = tri_pair(sbuf, c0, 2 * p + 1);
                gt4[p] = make_float4(lo2.x, lo2.y, hi2.x, hi2.y);
            }
        } else {
            const int n = NCELLS - c0;
            float2* gt2 = reinterpret_cast<float2*>(out + NV_ELEMS + (size_t)c0 * 6);
            for (int j = t; j < n * 3; j += BLK) gt2[j] = tri_pair(sbuf, c0, j);
        }

    } else {
        // ---------------- vmask blocks: one 4 KB contiguous write (512 cells)
        const int c0 = (bid - NBV - NBT) * (2 * BLK);
        #pragma unroll
        for (int r = 0; r < 2; ++r) {
            int cell = c0 + t + r * BLK;
            sbuf[t + r * BLK] = (cell < NCELLS) ? cell_mask(grid, cell) : 0.0f;
        }
        __syncthreads();

        float2* gm = reinterpret_cast<float2*>(out + NV_ELEMS + NT_ELEMS + (size_t)c0 * 4);
        const int n = min(2 * BLK, NCELLS - c0);
        if (n == 2 * BLK) {
            #pragma unroll
            for (int r = 0; r < 4; ++r) {   // lanes pairwise same-address: broadcast, free
                int g = t + r * BLK;
                float mm = sbuf[g >> 1];
                gm[g] = make_float2(mm, mm);
            }
        } else {
            for (int g = t; g < n * 2; g += BLK) {
                float mm = sbuf[g >> 1];
                gm[g] = make_float2(mm, mm);
            }
        }
    }
}

extern "C" void kernel_launch(void* const* d_in, const int* in_sizes, int n_in,
                              void* d_out, int out_size, void* d_ws, size_t ws_size,
                              hipStream_t stream) {
    const float* grid   = (const float*)d_in[0];   // [128,128,128] f32
    const float* deform = (const float*)d_in[1];   // [128,128,128,3] f32
    float* out = (float*)d_out;                    // [verts | tris | vmask] f32 concat

    int blocks = NBV + NBT + NBM;                  // 20,965
    mc_kernel<<<blocks, BLK, 0, stream>>>(grid, deform, out);
}

// Round 10
// 39.470 us; speedup vs baseline: 1.1465x; 1.1465x over previous
//
#include <hip/hip_runtime.h>
#include <stdint.h>

// Problem geometry (reference: 128^3 grid, padded to 130^3, cells = 129^3)
constexpr int DIM    = 128;
constexpr int NCX    = 129;
constexpr int NCELLS = NCX * NCX * NCX;            // 2,146,689 = 8385*256 + 129
constexpr size_t NV_ELEMS = (size_t)NCELLS * 12;   // verts region: 25,760,268 f32
constexpr size_t NT_ELEMS = (size_t)NCELLS * 6;    // tris  region: 12,880,134 f32
// vmask region: NCELLS*4 f32 ; total = 47,227,158 f32 elements
// Alignments: verts base 0 (16B ok); tris base = NV*4 = 103,041,072 B (16B ok);
// vmask base = (NV+NT)*4 = 154,561,608 B (8-mod-16 -> float2 only).

constexpr int BLK = 256;

__global__ __launch_bounds__(BLK) void mc_kernel(
    const float* __restrict__ grid,
    const float* __restrict__ deform,
    float*       __restrict__ out)
{
    // LDS staging: scatter-write per cell (strides 48/24/16 B tile the 32
    // banks exactly -> conflict-free), then contiguous coalesced copy-out.
    // Measured best structure: 39.7 us (= 87% of the 6.3 TB/s copy ceiling
    // on 217 MB mandatory traffic). nt stores, region-split blocks, higher
    // occupancy, and reduced LDS traffic all measured neutral or worse.
    __shared__ __align__(16) float sv[BLK * 12];   // verts  12,288 B
    __shared__ __align__(16) float st[BLK * 6];    // tris    6,144 B
    __shared__ __align__(16) float sm[BLK * 4];    // vmask   4,096 B

    const int t    = threadIdx.x;
    const int c0   = blockIdx.x * BLK;
    const int cell = c0 + t;

    if (cell < NCELLS) {
        // cell coords, z fastest (reference meshgrid 'ij' + C-order reshape)
        int z  = cell % NCX;
        int tt = cell / NCX;
        int y  = tt % NCX;
        int x  = tt / NCX;

        // 8 cube corners of padded grid; padding value 1.0 (> isovalue 0)
        float cmin = 3.4e38f, cmax = -3.4e38f;
        #pragma unroll
        for (int dx = 0; dx < 2; ++dx) {
            int i = x + dx - 1;
            bool iok = (unsigned)i < (unsigned)DIM;
            #pragma unroll
            for (int dy = 0; dy < 2; ++dy) {
                int j = y + dy - 1;
                bool jok = (unsigned)j < (unsigned)DIM;
                #pragma unroll
                for (int dz = 0; dz < 2; ++dz) {
                    int k = z + dz - 1;
                    bool kok = (unsigned)k < (unsigned)DIM;
                    float v = 1.0f;
                    if (iok && jok && kok)
                        v = grid[((size_t)i * DIM + j) * DIM + k];
                    cmin = fminf(cmin, v);
                    cmax = fmaxf(cmax, v);
                }
            }
        }
        float m = ((cmin <= 0.0f) && (cmax >= 0.0f)) ? 1.0f : 0.0f;

        // deform at padded index (x,y,z): zero in padding region
        float d0 = 0.f, d1 = 0.f, d2 = 0.f;
        {
            int i = x - 1, j = y - 1, k = z - 1;
            if ((unsigned)i < (unsigned)DIM && (unsigned)j < (unsigned)DIM &&
                (unsigned)k < (unsigned)DIM) {
                const float* b = deform + (((size_t)i * DIM + j) * DIM + k) * 3;
                d0 = b[0]; d1 = b[1]; d2 = b[2];
            }
        }
        float cx = (float)x + 0.5f + d0;
        float cy = (float)y + 0.5f + d1;
        float cz = (float)z + 0.5f + d2;

        // post-transform: (v - 1)/128 - 1 == v*(1/128) + (-(1/128) - 1)
        constexpr float S = 1.0f / 128.0f;
        constexpr float B = -(1.0f / 128.0f) - 1.0f;
        float ax = fmaf(cx - 0.3f, S, B) * m;   // OFFSET = 0.3
        float bx = fmaf(cx + 0.3f, S, B) * m;
        float ay = fmaf(cy - 0.3f, S, B) * m;
        float by = fmaf(cy + 0.3f, S, B) * m;
        float gz = fmaf(cz,        S, B) * m;

        // verts -> LDS: (ax,ay,gz)(bx,ay,gz)(bx,by,gz)(ax,by,gz)
        float4* v4 = reinterpret_cast<float4*>(sv) + t * 3;
        v4[0] = make_float4(ax, ay, gz, bx);
        v4[1] = make_float4(ay, gz, bx, by);
        v4[2] = make_float4(gz, ax, by, gz);

        // tris -> LDS: (4*cell + {0,1,2,0,2,3}) * mask  (exact in f32: < 2^24)
        float c4 = (float)(cell * 4);
        float2* t2 = reinterpret_cast<float2*>(st) + t * 3;
        t2[0] = make_float2(c4 * m,          (c4 + 1.0f) * m);
        t2[1] = make_float2((c4 + 2.0f) * m,  c4 * m);
        t2[2] = make_float2((c4 + 2.0f) * m, (c4 + 3.0f) * m);

        // vmask -> LDS
        reinterpret_cast<float4*>(sm)[t] = make_float4(m, m, m, m);
    }

    __syncthreads();

    // -------- coalesced copy-out --------
    float4*       gv  = reinterpret_cast<float4*>(out + (size_t)c0 * 12);
    const float4* lv  = reinterpret_cast<const float4*>(sv);
    float4*       gt4 = reinterpret_cast<float4*>(out + NV_ELEMS + (size_t)c0 * 6);
    const float4* lt4 = reinterpret_cast<const float4*>(st);
    float2*       gm  = reinterpret_cast<float2*>(out + NV_ELEMS + NT_ELEMS + (size_t)c0 * 4);
    const float2* lm  = reinterpret_cast<const float2*>(sm);

    if (c0 + BLK <= NCELLS) {
        // full block: compile-time trip counts, all stores wave-contiguous
        #pragma unroll
        for (int r = 0; r < 3; ++r) gv[t + r * BLK] = lv[t + r * BLK];   // 768 f4
        gt4[t] = lt4[t];                                                 // 384 f4
        if (t < BLK / 2) gt4[t + BLK] = lt4[t + BLK];
        #pragma unroll
        for (int r = 0; r < 2; ++r) gm[t + r * BLK] = lm[t + r * BLK];   // 512 f2
    } else {
        // tail block (129 cells)
        const int n = NCELLS - c0;
        for (int i = t; i < n * 3; i += BLK) gv[i] = lv[i];
        const float2* lt2 = reinterpret_cast<const float2*>(st);
        float2*       gt2 = reinterpret_cast<float2*>(out + NV_ELEMS + (size_t)c0 * 6);
        for (int i = t; i < n * 3; i += BLK) gt2[i] = lt2[i];
        for (int i = t; i < n * 2; i += BLK) gm[i] = lm[i];
    }
}

extern "C" void kernel_launch(void* const* d_in, const int* in_sizes, int n_in,
                              void* d_out, int out_size, void* d_ws, size_t ws_size,
                              hipStream_t stream) {
    const float* grid   = (const float*)d_in[0];   // [128,128,128] f32
    const float* deform = (const float*)d_in[1];   // [128,128,128,3] f32
    float* out = (float*)d_out;                    // [verts | tris | vmask] f32 concat

    int blocks = (NCELLS + BLK - 1) / BLK;         // 8386
    mc_kernel<<<blocks, BLK, 0, stream>>>(grid, deform, out);
}